// Round 8
// baseline (200.091 us; speedup 1.0000x reference)
//
#include <hip/hip_runtime.h>
#include <hip/hip_bf16.h>
#include <math.h>

#define En   8
#define Bn   4096
#define Ln   512
#define K1n  1024   // 2L
#define H1n  1024
#define H2n  512
#define Cn   40
#define NP3  48     // layer-3 padded N

typedef unsigned short u16;
typedef __attribute__((ext_vector_type(8))) short bf16x8;   // 8 bf16 = 4 VGPRs
typedef __attribute__((ext_vector_type(4))) float f32x4;

// f32 -> bf16 (RNE), finite inputs
__device__ __forceinline__ u16 f2b(float f) {
    union { float f; unsigned int u; } v; v.f = f;
    unsigned int r = v.u + 0x7FFF + ((v.u >> 16) & 1);
    return (u16)(r >> 16);
}

// async global->LDS 16B copy (global_load_lds_dwordx4); LDS dest lane-contiguous.
__device__ __forceinline__ void g2l16(const void* g, void* l) {
    __builtin_amdgcn_global_load_lds(
        (const __attribute__((address_space(1))) unsigned int*)(unsigned long long)g,
        (__attribute__((address_space(3))) unsigned int*)(unsigned int)(unsigned long long)l,
        16, 0, 0);
}

// ---------------------------------------------------------------------------
// Prep (block-partitioned):
//   0           : routing -> meta, perm
//   1..256      : x concat + f32->bf16 (original order) -> Xb
//   257..384    : W3 [e][512][40] f32 -> W3t [e][48][512] bf16 (pad 0)
//   385..448    : out[b][c] = b3[label[b]][c]  (bias pre-init for L3 atomics)
// ---------------------------------------------------------------------------
#define PB_X0   1
#define PB_X    256
#define PB_W3   128
#define PB_OUT  64
#define PB_TOT  (PB_X0 + PB_X + PB_W3 + PB_OUT)

__global__ __launch_bounds__(256) void prep_kernel(
    const float* __restrict__ xs, const float* __restrict__ xp,
    const float* __restrict__ W3, const float* __restrict__ b3,
    const int* __restrict__ label,
    int* __restrict__ meta, int* __restrict__ perm,
    u16* __restrict__ Xb, u16* __restrict__ W3t,
    float* __restrict__ out)
{
    __shared__ __align__(16) float sm[32 * 41];
    const int bid = blockIdx.x;
    const int tid = threadIdx.x;

    if (bid == 0) {
        // ---- routing ----
        __shared__ int cnt[En], off[En + 1];
        if (tid < En) cnt[tid] = 0;
        __syncthreads();
        for (int b = tid; b < Bn; b += 256) atomicAdd(&cnt[label[b]], 1);
        __syncthreads();
        if (tid == 0) {
            int run = 0;
            for (int e = 0; e < En; e++) { off[e] = run; run += cnt[e]; }
            off[En] = run;
        }
        __syncthreads();
        if (tid < En) cnt[tid] = off[tid];
        __syncthreads();
        for (int b = tid; b < Bn; b += 256) {
            int e = label[b];
            perm[atomicAdd(&cnt[e], 1)] = b;
        }
        if (tid <= En) meta[tid] = off[tid];
    } else if (bid < PB_X0 + PB_X) {
        // ---- x concat + convert (original order), 16 rows/block ----
        int r0 = (bid - PB_X0) * 16;
        #pragma unroll 4
        for (int s = 0; s < 16; s++) {
            int r = r0 + s;
            int k = tid * 4;
            const float* src = (k < Ln) ? (xp + (size_t)r * Ln + k)
                                        : (xs + (size_t)r * Ln + (k - Ln));
            float4 v = *(const float4*)src;
            *(ushort4*)&Xb[(size_t)r * K1n + k] =
                make_ushort4(f2b(v.x), f2b(v.y), f2b(v.z), f2b(v.w));
        }
    } else if (bid < PB_X0 + PB_X + PB_W3) {
        // ---- W3: [512][40] f32 -> [48][512] bf16, pad cols 40..47 ----
        int b = bid - (PB_X0 + PB_X);
        int e = b >> 4, k0 = (b & 15) * 32;
        const float* src = W3 + (size_t)e * H2n * Cn;
        u16* dst = W3t + (size_t)e * NP3 * H2n;
        #pragma unroll
        for (int s = 0; s < 5; s++) {             // 32*40 = 1280
            int idx = tid + s * 256;
            int kk = idx / Cn, nn = idx - kk * Cn;
            if (kk < 32) sm[kk * 41 + nn] = src[(size_t)(k0 + kk) * Cn + nn];
        }
        __syncthreads();
        #pragma unroll
        for (int s = 0; s < 6; s++) {             // 48*32 = 1536
            int idx = tid + s * 256;
            int nn = idx >> 5, kk = idx & 31;
            float v = (nn < Cn) ? sm[kk * 41 + nn] : 0.f;
            dst[(size_t)nn * H2n + k0 + kk] = f2b(v);
        }
    } else {
        // ---- out bias pre-init: out[r][c] = b3[label[r]][c], 64 rows/block ----
        int b = bid - (PB_X0 + PB_X + PB_W3);
        int r0 = b * 64;
        #pragma unroll
        for (int s = 0; s < 10; s++) {            // 64*40 = 2560
            int idx = tid + s * 256;
            int r = r0 + idx / Cn;
            int c = idx - (idx / Cn) * Cn;
            out[(size_t)r * Cn + c] = b3[label[r] * Cn + c];
        }
    }
}

// ---------------------------------------------------------------------------
// B-stage: write a 4k x 4n register micro-tile pair into LDS [n][k] bf16 with
// bank swizzle sigma(n) = (n ^ (n>>2)) & 7 applied to the k-chunk (8-granular,
// but 4-aligned packs stay contiguous since XOR only touches bits 3..5).
// ---------------------------------------------------------------------------
__device__ __forceinline__ void bstore(
    const float4 wreg[2][4], u16* __restrict__ Bst, int kg, int n4)
{
    #pragma unroll
    for (int p = 0; p < 2; p++) {
        int k0 = (kg + p * 8) * 4;
        float4 a0 = wreg[p][0], a1 = wreg[p][1], a2 = wreg[p][2], a3 = wreg[p][3];
        ushort4 o[4];
        o[0] = make_ushort4(f2b(a0.x), f2b(a1.x), f2b(a2.x), f2b(a3.x));
        o[1] = make_ushort4(f2b(a0.y), f2b(a1.y), f2b(a2.y), f2b(a3.y));
        o[2] = make_ushort4(f2b(a0.z), f2b(a1.z), f2b(a2.z), f2b(a3.z));
        o[3] = make_ushort4(f2b(a0.w), f2b(a1.w), f2b(a2.w), f2b(a3.w));
        #pragma unroll
        for (int i = 0; i < 4; i++) {
            int n = n4 + i;
            int sig = (n ^ (n >> 2)) & 7;
            *(ushort4*)&Bst[n * 64 + (k0 ^ (sig << 3))] = o[i];
        }
    }
}

// ---------------------------------------------------------------------------
// Grouped bf16 MFMA GEMM, 128x128 tile, BK=64, double-buffered K-loop.
// A: bf16 (GATHER: original order via perm; else sorted), staged via async DMA.
// W: native [e][k][n] FP32 — staged via register transpose + f32->bf16 (bstore).
// FUSE3: layer-3 k-split in the epilogue (h-tile -> LDS -> MFMA vs Wt3 ->
// atomicAdd f32 into outf, pre-initialized with b3 by prep).
// ---------------------------------------------------------------------------
template <int K, int N, bool GATHER, bool FUSE3>
__global__ __launch_bounds__(256) void mfma_gemm(
    const u16* __restrict__ A, const float* __restrict__ Wf,
    const float* __restrict__ bias, const int* __restrict__ meta,
    const int* __restrict__ perm, u16* __restrict__ outb,
    const u16* __restrict__ Wt3, float* __restrict__ outf)
{
    constexpr int TM = 128, TN = 128, BK = 64;
    constexpr int T = K / BK;
    __shared__ __align__(16) u16 SM[32768];   // 2 stages x (A 16KB + B 16KB)

    const int tid = threadIdx.x;
    const int bx = blockIdx.x;

    int expert = -1, row0 = 0, rowmax = 0, acc_t = 0;
    int prev = meta[0];
    #pragma unroll
    for (int e = 0; e < En; e++) {
        int nxt = meta[e + 1];
        int c = nxt - prev;
        int t = (c + TM - 1) / TM;
        if (expert < 0 && bx < acc_t + t) {
            expert = e; row0 = prev + (bx - acc_t) * TM; rowmax = nxt - 1;
        }
        acc_t += t; prev = nxt;
    }
    if (expert < 0) return;

    const int col0 = blockIdx.y * TN;
    const float* Wexp = Wf + (size_t)expert * K * N;

    const int lane = tid & 63;
    const int wid = tid >> 6;
    const int wm = (wid & 1) * 64;
    const int wn = (wid >> 1) * 64;
    const int l15 = lane & 15;
    const int lq = lane >> 4;

    // A staging slots: idx = tid + s*256; row rl=idx>>3, chunk pos c=idx&7 holds
    // global k-chunk (c ^ (rl&7)); LDS offset = idx*8 u16 (lane-contiguous).
    const u16* aptr[4];
    int aoff[4];
    #pragma unroll
    for (int s = 0; s < 4; s++) {
        int idx = tid + s * 256;
        int rl = idx >> 3, c = idx & 7;
        int kq = c ^ (rl & 7);
        int rg = row0 + rl; if (rg > rowmax) rg = rowmax;
        if (GATHER) rg = perm[rg];
        aptr[s] = A + (size_t)rg * K + kq * 8;
        aoff[s] = idx * 8;
    }
    const int csw = l15 & 7;

    // B load geometry: n4 = 4 consecutive cols, kg selects 4-k row group
    const int n4 = (tid & 31) * 4;
    const int kg = tid >> 5;          // 0..7

    // B frag swizzle per j (n = wn + j*16 + l15)
    int sB[4];
    #pragma unroll
    for (int j = 0; j < 4; j++) {
        int n = wn + j * 16 + l15;
        sB[j] = (n ^ (n >> 2)) & 7;
    }

    f32x4 acc[4][4];
    #pragma unroll
    for (int i = 0; i < 4; i++)
        #pragma unroll
        for (int j = 0; j < 4; j++) acc[i][j] = (f32x4){0.f, 0.f, 0.f, 0.f};

    // prologue: tile 0 -> stage 0
    float4 wreg[2][4];
    #pragma unroll
    for (int p = 0; p < 2; p++)
        #pragma unroll
        for (int d = 0; d < 4; d++)
            wreg[p][d] = *(const float4*)&Wexp[(size_t)((kg + p * 8) * 4 + d) * N + col0 + n4];
    #pragma unroll
    for (int s = 0; s < 4; s++) g2l16(aptr[s], &SM[aoff[s]]);
    bstore(wreg, &SM[8192], kg, n4);

    for (int t = 0; t < T; t++) {
        __syncthreads();
        const u16* As = &SM[(t & 1) * 16384];
        const u16* Bs = As + 8192;
        if (t + 1 < T) {
            int base = ((t + 1) & 1) * 16384;
            int ko = (t + 1) * BK;
            #pragma unroll
            for (int s = 0; s < 4; s++)
                g2l16(aptr[s] + ko, &SM[base + aoff[s]]);
            #pragma unroll
            for (int p = 0; p < 2; p++)
                #pragma unroll
                for (int d = 0; d < 4; d++)
                    wreg[p][d] = *(const float4*)
                        &Wexp[(size_t)(ko + (kg + p * 8) * 4 + d) * N + col0 + n4];
        }
        bf16x8 af[4][2], bf[4][2];
        #pragma unroll
        for (int h = 0; h < 2; h++) {
            #pragma unroll
            for (int i = 0; i < 4; i++)
                af[i][h] = *(const bf16x8*)
                    &As[(wm + i * 16 + l15) * 64 + (((h * 4 + lq) ^ csw) << 3)];
            #pragma unroll
            for (int j = 0; j < 4; j++)
                bf[j][h] = *(const bf16x8*)
                    &Bs[(wn + j * 16 + l15) * 64 + (((h * 4 + lq) ^ sB[j]) << 3)];
        }
        #pragma unroll
        for (int h = 0; h < 2; h++)
            #pragma unroll
            for (int i = 0; i < 4; i++)
                #pragma unroll
                for (int j = 0; j < 4; j++)
                    acc[i][j] = __builtin_amdgcn_mfma_f32_16x16x32_bf16(
                        af[i][h], bf[j][h], acc[i][j], 0, 0, 0);
        if (t + 1 < T)
            bstore(wreg, &SM[((t + 1) & 1) * 16384 + 8192], kg, n4);
    }

    if (!FUSE3) {
        // epilogue: bias + ELU -> global bf16.  C/D: col=l15, row=lq*4+reg
        #pragma unroll
        for (int i = 0; i < 4; i++) {
            #pragma unroll
            for (int j = 0; j < 4; j++) {
                int col = col0 + wn + j * 16 + l15;
                float bv = bias[expert * N + col];
                #pragma unroll
                for (int r = 0; r < 4; r++) {
                    int grow = row0 + wm + i * 16 + lq * 4 + r;
                    if (grow <= rowmax) {
                        float v = acc[i][j][r] + bv;
                        v = (v > 0.f) ? v : (expf(v) - 1.f);
                        outb[(size_t)grow * N + col] = f2b(v);
                    }
                }
            }
        }
    } else {
        // ---- fused layer 3 (k-split over this block's 128 h-cols) ----
        __syncthreads();                 // all LDS reads of K-loop done
        u16* H = &SM[0];                 // [128][136] bf16
        #pragma unroll
        for (int i = 0; i < 4; i++) {
            #pragma unroll
            for (int j = 0; j < 4; j++) {
                int col = wn + j * 16 + l15;
                float bv = bias[expert * N + col0 + col];
                #pragma unroll
                for (int r = 0; r < 4; r++) {
                    float v = acc[i][j][r] + bv;
                    v = (v > 0.f) ? v : (expf(v) - 1.f);
                    H[(wm + i * 16 + lq * 4 + r) * 136 + col] = f2b(v);
                }
            }
        }
        __syncthreads();
        const int rh = (wid & 1) * 64;
        const int kb = (wid >> 1) * 64;
        f32x4 a3[4][3];
        #pragma unroll
        for (int i = 0; i < 4; i++)
            #pragma unroll
            for (int j = 0; j < 3; j++) a3[i][j] = (f32x4){0.f, 0.f, 0.f, 0.f};
        #pragma unroll
        for (int ki = 0; ki < 2; ki++) {
            int kl = kb + ki * 32;
            bf16x8 ha[4];
            #pragma unroll
            for (int i = 0; i < 4; i++)
                ha[i] = *(const bf16x8*)&H[(rh + i * 16 + l15) * 136 + kl + lq * 8];
            #pragma unroll
            for (int j = 0; j < 3; j++) {
                bf16x8 wb = *(const bf16x8*)
                    &Wt3[((size_t)expert * NP3 + j * 16 + l15) * H2n + col0 + kl + lq * 8];
                #pragma unroll
                for (int i = 0; i < 4; i++)
                    a3[i][j] = __builtin_amdgcn_mfma_f32_16x16x32_bf16(
                        ha[i], wb, a3[i][j], 0, 0, 0);
            }
        }
        #pragma unroll
        for (int j = 0; j < 3; j++) {
            int col = j * 16 + l15;
            if (col < Cn) {
                #pragma unroll
                for (int i = 0; i < 4; i++) {
                    #pragma unroll
                    for (int r = 0; r < 4; r++) {
                        int grow = row0 + rh + i * 16 + lq * 4 + r;
                        if (grow <= rowmax)
                            atomicAdd(&outf[(size_t)perm[grow] * Cn + col], a3[i][j][r]);
                    }
                }
            }
        }
    }
}

// ---------------------------------------------------------------------------
extern "C" void kernel_launch(void* const* d_in, const int* in_sizes, int n_in,
                              void* d_out, int out_size, void* d_ws, size_t ws_size,
                              hipStream_t stream)
{
    const float* xs = (const float*)d_in[0];
    const float* xp = (const float*)d_in[1];
    const float* W1 = (const float*)d_in[2];
    const float* b1 = (const float*)d_in[3];
    const float* W2 = (const float*)d_in[4];
    const float* b2 = (const float*)d_in[5];
    const float* W3 = (const float*)d_in[6];
    const float* b3 = (const float*)d_in[7];
    const int* label = (const int*)d_in[8];
    float* out = (float*)d_out;

    char* ws = (char*)d_ws;
    int* meta = (int*)ws;                                    // 64 B
    int* perm = (int*)(ws + 64);                             // 16 KB
    u16* Xb  = (u16*)(ws + (64 << 10));                      // 8 MB [4096][1024] (orig order)
    u16* h1b = (u16*)(ws + (64 << 10) + (8 << 20));          // 8 MB [4096][1024] (sorted)
    u16* W3t = (u16*)(ws + (64 << 10) + (16 << 20));         // 393 KB [8][48][512]

    prep_kernel<<<PB_TOT, 256, 0, stream>>>(
        xs, xp, W3, b3, label, meta, perm, Xb, W3t, out);

    // L1: row tiles <= 4096/128 + 8 = 40; cols 1024/128 = 8
    mfma_gemm<K1n, H1n, true, false><<<dim3(40, 8), 256, 0, stream>>>(
        Xb, W1, b1, meta, perm, h1b, nullptr, nullptr);

    // L2 (+fused L3): cols 512/128 = 4
    mfma_gemm<H1n, H2n, false, true><<<dim3(40, 4), 256, 0, stream>>>(
        h1b, W2, b2, meta, perm, nullptr, W3t, out);
}

// Round 9
// 173.580 us; speedup vs baseline: 1.1527x; 1.1527x over previous
//
#include <hip/hip_runtime.h>
#include <hip/hip_bf16.h>
#include <math.h>

#define En   8
#define Bn   4096
#define Ln   512
#define K1n  1024   // 2L
#define H1n  1024
#define H2n  512
#define Cn   40
#define NP3  48     // layer-3 padded N

typedef unsigned short u16;
typedef __attribute__((ext_vector_type(8))) short bf16x8;   // 8 bf16 = 4 VGPRs
typedef __attribute__((ext_vector_type(4))) float f32x4;

// f32 -> bf16 (RNE), finite inputs
__device__ __forceinline__ u16 f2b(float f) {
    union { float f; unsigned int u; } v; v.f = f;
    unsigned int r = v.u + 0x7FFF + ((v.u >> 16) & 1);
    return (u16)(r >> 16);
}

// async global->LDS 16B copy (global_load_lds_dwordx4); LDS dest lane-contiguous.
__device__ __forceinline__ void g2l16(const void* g, void* l) {
    __builtin_amdgcn_global_load_lds(
        (const __attribute__((address_space(1))) unsigned int*)(unsigned long long)g,
        (__attribute__((address_space(3))) unsigned int*)(unsigned int)(unsigned long long)l,
        16, 0, 0);
}

// ---------------------------------------------------------------------------
// Mega-prep, block-partitioned independent jobs (R7 structure):
//   0            : routing -> meta, perm
//   1..256       : x concat + f32->bf16 (original order) -> Xb
//   ..+2048      : W1 [e][k][n] f32 -> W1t [e][n][k] bf16
//   ..+1024      : W2 likewise
//   ..+128       : W3 [e][512][40] -> W3t [e][48][512] bf16 (pad 0)
//   ..+64        : out[b][c] = b3[label[b]][c]  (bias pre-init for L3 atomics)
// ---------------------------------------------------------------------------
#define PB_X0   1
#define PB_X    256
#define PB_W1   2048
#define PB_W2   1024
#define PB_W3   128
#define PB_OUT  64
#define PB_TOT  (PB_X0 + PB_X + PB_W1 + PB_W2 + PB_W3 + PB_OUT)

__device__ __forceinline__ void wtrans64(
    const float* __restrict__ Wsrc, u16* __restrict__ Wdst,
    int K, int N, int k0, int n0, int tid, float* sm /* [64][65] */)
{
    #pragma unroll
    for (int s = 0; s < 4; s++) {
        int idx = tid + s * 256;
        int kk = idx >> 4, c4 = (idx & 15) * 4;
        float4 v = *(const float4*)&Wsrc[(size_t)(k0 + kk) * N + n0 + c4];
        float* row = sm + kk * 65 + c4;
        row[0] = v.x; row[1] = v.y; row[2] = v.z; row[3] = v.w;
    }
    __syncthreads();
    #pragma unroll
    for (int s = 0; s < 4; s++) {
        int idx = tid + s * 256;
        int nn = idx >> 4, kc = (idx & 15) * 4;
        ushort4 o = make_ushort4(f2b(sm[(kc + 0) * 65 + nn]), f2b(sm[(kc + 1) * 65 + nn]),
                                 f2b(sm[(kc + 2) * 65 + nn]), f2b(sm[(kc + 3) * 65 + nn]));
        *(ushort4*)&Wdst[(size_t)(n0 + nn) * K + k0 + kc] = o;
    }
}

__global__ __launch_bounds__(256) void prep_kernel(
    const float* __restrict__ xs, const float* __restrict__ xp,
    const float* __restrict__ W1, const float* __restrict__ W2,
    const float* __restrict__ W3, const float* __restrict__ b3,
    const int* __restrict__ label,
    int* __restrict__ meta, int* __restrict__ perm,
    u16* __restrict__ Xb, u16* __restrict__ W1t,
    u16* __restrict__ W2t, u16* __restrict__ W3t,
    float* __restrict__ out)
{
    __shared__ __align__(16) float sm[64 * 65];
    const int bid = blockIdx.x;
    const int tid = threadIdx.x;

    if (bid == 0) {
        // ---- routing ----
        int* cnt = (int*)sm;
        int* off = cnt + En;
        if (tid < En) cnt[tid] = 0;
        __syncthreads();
        for (int b = tid; b < Bn; b += 256) atomicAdd(&cnt[label[b]], 1);
        __syncthreads();
        if (tid == 0) {
            int run = 0;
            for (int e = 0; e < En; e++) { off[e] = run; run += cnt[e]; }
            off[En] = run;
        }
        __syncthreads();
        if (tid < En) cnt[tid] = off[tid];
        __syncthreads();
        for (int b = tid; b < Bn; b += 256) {
            int e = label[b];
            perm[atomicAdd(&cnt[e], 1)] = b;
        }
        if (tid <= En) meta[tid] = off[tid];
    } else if (bid < PB_X0 + PB_X) {
        // ---- x concat + convert (original order), 16 rows/block ----
        int r0 = (bid - PB_X0) * 16;
        #pragma unroll 4
        for (int s = 0; s < 16; s++) {
            int r = r0 + s;
            int k = tid * 4;
            const float* src = (k < Ln) ? (xp + (size_t)r * Ln + k)
                                        : (xs + (size_t)r * Ln + (k - Ln));
            float4 v = *(const float4*)src;
            *(ushort4*)&Xb[(size_t)r * K1n + k] =
                make_ushort4(f2b(v.x), f2b(v.y), f2b(v.z), f2b(v.w));
        }
    } else if (bid < PB_X0 + PB_X + PB_W1) {
        int b = bid - (PB_X0 + PB_X);
        int e = b >> 8, rem = b & 255;
        int k0 = (rem >> 4) * 64, n0 = (rem & 15) * 64;
        wtrans64(W1 + (size_t)e * K1n * H1n, W1t + (size_t)e * H1n * K1n,
                 K1n, H1n, k0, n0, tid, sm);
    } else if (bid < PB_X0 + PB_X + PB_W1 + PB_W2) {
        int b = bid - (PB_X0 + PB_X + PB_W1);
        int e = b >> 7, rem = b & 127;
        int k0 = (rem >> 3) * 64, n0 = (rem & 7) * 64;
        wtrans64(W2 + (size_t)e * H1n * H2n, W2t + (size_t)e * H2n * H1n,
                 H1n, H2n, k0, n0, tid, sm);
    } else if (bid < PB_X0 + PB_X + PB_W1 + PB_W2 + PB_W3) {
        // ---- W3: [512][40] f32 -> [48][512] bf16, pad cols 40..47 ----
        int b = bid - (PB_X0 + PB_X + PB_W1 + PB_W2);
        int e = b >> 4, k0 = (b & 15) * 32;
        const float* src = W3 + (size_t)e * H2n * Cn;
        u16* dst = W3t + (size_t)e * NP3 * H2n;
        float* t = sm;                            // [32][41]
        #pragma unroll
        for (int s = 0; s < 5; s++) {
            int idx = tid + s * 256;
            int kk = idx / Cn, nn = idx - kk * Cn;
            if (kk < 32) t[kk * 41 + nn] = src[(size_t)(k0 + kk) * Cn + nn];
        }
        __syncthreads();
        #pragma unroll
        for (int s = 0; s < 6; s++) {
            int idx = tid + s * 256;
            int nn = idx >> 5, kk = idx & 31;
            float v = (nn < Cn) ? t[kk * 41 + nn] : 0.f;
            dst[(size_t)nn * H2n + k0 + kk] = f2b(v);
        }
    } else {
        // ---- out bias pre-init: out[r][c] = b3[label[r]][c], 64 rows/block ----
        int b = bid - (PB_X0 + PB_X + PB_W1 + PB_W2 + PB_W3);
        int r0 = b * 64;
        #pragma unroll
        for (int s = 0; s < 10; s++) {
            int idx = tid + s * 256;
            int r = r0 + idx / Cn;
            int c = idx - (idx / Cn) * Cn;
            out[(size_t)r * Cn + c] = b3[label[r] * Cn + c];
        }
    }
}

// ---------------------------------------------------------------------------
// Grouped bf16 MFMA GEMM, 64x64 tile, BK=32, double-buffered async K-loop.
// Small tiles -> big grid (L1: 1152 blocks) so latency hides via occupancy.
// 4 waves per block, each computing a 32x32 quadrant (2x2 of 16x16x32 MFMA).
// A: bf16 (GATHER: original order via perm; else sorted);  Wt: [E][N][K] bf16.
// FUSE3: layer-3 k-split epilogue (h-tile -> LDS -> MFMA vs Wt3 -> atomicAdd
// into outf, pre-initialized with b3 by prep).
// ---------------------------------------------------------------------------
template <int K, int N, bool GATHER, bool FUSE3>
__global__ __launch_bounds__(256) void mfma_gemm(
    const u16* __restrict__ A, const u16* __restrict__ Wt,
    const float* __restrict__ bias, const int* __restrict__ meta,
    const int* __restrict__ perm, u16* __restrict__ outb,
    const u16* __restrict__ Wt3, float* __restrict__ outf)
{
    constexpr int TM = 64, TN = 64, BK = 32;
    constexpr int T = K / BK;
    // 2 stages x (A 4KB + B 4KB) = 16 KB; fused-L3 H tile (64x72 u16) reuses it.
    __shared__ __align__(16) u16 SM[8192];

    const int tid = threadIdx.x;
    const int bx = blockIdx.x;

    int expert = -1, row0 = 0, rowmax = 0, acc_t = 0;
    int prev = meta[0];
    #pragma unroll
    for (int e = 0; e < En; e++) {
        int nxt = meta[e + 1];
        int c = nxt - prev;
        int t = (c + TM - 1) / TM;
        if (expert < 0 && bx < acc_t + t) {
            expert = e; row0 = prev + (bx - acc_t) * TM; rowmax = nxt - 1;
        }
        acc_t += t; prev = nxt;
    }
    if (expert < 0) return;

    const int col0 = blockIdx.y * TN;
    const u16* Wexp = Wt + (size_t)expert * N * K;

    const int lane = tid & 63;
    const int wid = tid >> 6;
    const int wm = (wid & 1) * 32;      // wave row-quadrant (32)
    const int wn = (wid >> 1) * 32;     // wave col-quadrant (32)
    const int l15 = lane & 15;
    const int lq = lane >> 4;

    // staging: 64 rows x 4 chunks = 256 slots per matrix = 1 per thread.
    // slot tid: row rl = tid>>2, chunk pos c = tid&3 holds k-chunk c^(rl&3).
    const int rl = tid >> 2, cch = tid & 3;
    const int kq = cch ^ (rl & 3);
    int rg = row0 + rl; if (rg > rowmax) rg = rowmax;
    if (GATHER) rg = perm[rg];
    const u16* aptr = A + (size_t)rg * K + kq * 8;
    const u16* bptr = Wexp + (size_t)(col0 + rl) * K + kq * 8;
    const int aoff = tid * 8;            // A slots [0, 2048)
    const int boff = 2048 + tid * 8;     // B slots [2048, 4096)
    const int ksw = (lq ^ (l15 & 3)) * 8;

    f32x4 acc[2][2];
    #pragma unroll
    for (int i = 0; i < 2; i++)
        #pragma unroll
        for (int j = 0; j < 2; j++) acc[i][j] = (f32x4){0.f, 0.f, 0.f, 0.f};

    // prologue: tile 0 -> stage 0
    g2l16(aptr, &SM[aoff]);
    g2l16(bptr, &SM[boff]);

    for (int t = 0; t < T; t++) {
        __syncthreads();    // drains this tile's DMA (issued last iter)
        const u16* As = &SM[(t & 1) * 4096];
        const u16* Bs = As + 2048;
        if (t + 1 < T) {    // prefetch next tile into the other stage
            int base = ((t + 1) & 1) * 4096;
            int ko = (t + 1) * BK;
            g2l16(aptr + ko, &SM[base + aoff]);
            g2l16(bptr + ko, &SM[base + boff]);
        }
        bf16x8 af[2], bf[2];
        #pragma unroll
        for (int i = 0; i < 2; i++)
            af[i] = *(const bf16x8*)&As[(wm + i * 16 + l15) * BK + ksw];
        #pragma unroll
        for (int j = 0; j < 2; j++)
            bf[j] = *(const bf16x8*)&Bs[(wn + j * 16 + l15) * BK + ksw];
        #pragma unroll
        for (int i = 0; i < 2; i++)
            #pragma unroll
            for (int j = 0; j < 2; j++)
                acc[i][j] = __builtin_amdgcn_mfma_f32_16x16x32_bf16(
                    af[i], bf[j], acc[i][j], 0, 0, 0);
    }

    if (!FUSE3) {
        // epilogue: bias + ELU -> global bf16.  C/D: col=l15, row=lq*4+reg
        #pragma unroll
        for (int i = 0; i < 2; i++) {
            #pragma unroll
            for (int j = 0; j < 2; j++) {
                int col = col0 + wn + j * 16 + l15;
                float bv = bias[expert * N + col];
                #pragma unroll
                for (int r = 0; r < 4; r++) {
                    int grow = row0 + wm + i * 16 + lq * 4 + r;
                    if (grow <= rowmax) {
                        float v = acc[i][j][r] + bv;
                        v = (v > 0.f) ? v : (expf(v) - 1.f);
                        outb[(size_t)grow * N + col] = f2b(v);
                    }
                }
            }
        }
    } else {
        // ---- fused layer 3: k-split over this block's 64 h-cols ----
        __syncthreads();                 // all K-loop LDS reads done
        u16* H = &SM[0];                 // [64][72] bf16 (9.2 KB)
        #pragma unroll
        for (int i = 0; i < 2; i++) {
            #pragma unroll
            for (int j = 0; j < 2; j++) {
                int col = wn + j * 16 + l15;
                float bv = bias[expert * N + col0 + col];
                #pragma unroll
                for (int r = 0; r < 4; r++) {
                    float v = acc[i][j][r] + bv;
                    v = (v > 0.f) ? v : (expf(v) - 1.f);
                    H[(wm + i * 16 + lq * 4 + r) * 72 + col] = f2b(v);
                }
            }
        }
        __syncthreads();
        // wave wid handles rows rh..rh+15, k = full 64 local h-cols (2x32)
        const int rh = wid * 16;
        f32x4 a3[3];
        #pragma unroll
        for (int j = 0; j < 3; j++) a3[j] = (f32x4){0.f, 0.f, 0.f, 0.f};
        #pragma unroll
        for (int ki = 0; ki < 2; ki++) {
            bf16x8 ha = *(const bf16x8*)&H[(rh + l15) * 72 + ki * 32 + lq * 8];
            #pragma unroll
            for (int j = 0; j < 3; j++) {
                bf16x8 wb = *(const bf16x8*)
                    &Wt3[((size_t)expert * NP3 + j * 16 + l15) * H2n + col0 + ki * 32 + lq * 8];
                a3[j] = __builtin_amdgcn_mfma_f32_16x16x32_bf16(ha, wb, a3[j], 0, 0, 0);
            }
        }
        #pragma unroll
        for (int j = 0; j < 3; j++) {
            int col = j * 16 + l15;
            if (col < Cn) {
                #pragma unroll
                for (int r = 0; r < 4; r++) {
                    int grow = row0 + rh + lq * 4 + r;
                    if (grow <= rowmax)
                        atomicAdd(&outf[(size_t)perm[grow] * Cn + col], a3[j][r]);
                }
            }
        }
    }
}

// ---------------------------------------------------------------------------
extern "C" void kernel_launch(void* const* d_in, const int* in_sizes, int n_in,
                              void* d_out, int out_size, void* d_ws, size_t ws_size,
                              hipStream_t stream)
{
    const float* xs = (const float*)d_in[0];
    const float* xp = (const float*)d_in[1];
    const float* W1 = (const float*)d_in[2];
    const float* b1 = (const float*)d_in[3];
    const float* W2 = (const float*)d_in[4];
    const float* b2 = (const float*)d_in[5];
    const float* W3 = (const float*)d_in[6];
    const float* b3 = (const float*)d_in[7];
    const int* label = (const int*)d_in[8];
    float* out = (float*)d_out;

    char* ws = (char*)d_ws;
    int* meta = (int*)ws;                                    // 64 B
    int* perm = (int*)(ws + 64);                             // 16 KB
    u16* Xb  = (u16*)(ws + (64 << 10));                      // 8 MB [4096][1024] (orig order)
    u16* W1t = (u16*)(ws + (64 << 10) + (8  << 20));         // 16 MB [8][1024][1024]
    u16* W2t = (u16*)(ws + (64 << 10) + (24 << 20));         // 8 MB  [8][512][1024]
    u16* h1b = (u16*)(ws + (64 << 10) + (32 << 20));         // 8 MB  [4096][1024] (sorted)
    u16* W3t = (u16*)(ws + (64 << 10) + (40 << 20));         // 393 KB [8][48][512]

    prep_kernel<<<PB_TOT, 256, 0, stream>>>(
        xs, xp, W1, W2, W3, b3, label, meta, perm, Xb, W1t, W2t, W3t, out);

    // L1: row tiles <= 4096/64 + 8 = 72; cols 1024/64 = 16 -> 1152 blocks
    mfma_gemm<K1n, H1n, true, false><<<dim3(72, 16), 256, 0, stream>>>(
        Xb, W1t, b1, meta, perm, h1b, nullptr, nullptr);

    // L2 (+fused L3): cols 512/64 = 8 -> 576 blocks
    mfma_gemm<H1n, H2n, false, true><<<dim3(72, 8), 256, 0, stream>>>(
        h1b, W2t, b2, meta, perm, nullptr, W3t, out);
}

// Round 10
// 172.080 us; speedup vs baseline: 1.1628x; 1.0087x over previous
//
#include <hip/hip_runtime.h>
#include <hip/hip_bf16.h>
#include <math.h>

#define En   8
#define Bn   4096
#define Ln   512
#define K1n  1024   // 2L
#define H1n  1024
#define H2n  512
#define Cn   40
#define NP3  48     // layer-3 padded N
#define NTR  72     // max row tiles at TM=64 (4096/64 + 8)

typedef unsigned short u16;
typedef __attribute__((ext_vector_type(8))) short bf16x8;
typedef __attribute__((ext_vector_type(4))) float f32x4;

// f32 -> bf16 (RNE), finite inputs
__device__ __forceinline__ u16 f2b(float f) {
    union { float f; unsigned int u; } v; v.f = f;
    unsigned int r = v.u + 0x7FFF + ((v.u >> 16) & 1);
    return (u16)(r >> 16);
}

// async global->LDS 16B copy; LDS dest must be wave-uniform base + lane*16.
__device__ __forceinline__ void g2l16(const void* g, void* l) {
    __builtin_amdgcn_global_load_lds(
        (const __attribute__((address_space(1))) unsigned int*)(unsigned long long)g,
        (__attribute__((address_space(3))) unsigned int*)(unsigned int)(unsigned long long)l,
        16, 0, 0);
}

// 64x64 f32->bf16 transpose tile via LDS
__device__ __forceinline__ void wtrans64(
    const float* __restrict__ Wsrc, u16* __restrict__ Wdst,
    int K, int N, int k0, int n0, int tid, float* sm /* [64][65] */)
{
    #pragma unroll
    for (int s = 0; s < 4; s++) {
        int idx = tid + s * 256;
        int kk = idx >> 4, c4 = (idx & 15) * 4;
        float4 v = *(const float4*)&Wsrc[(size_t)(k0 + kk) * N + n0 + c4];
        float* row = sm + kk * 65 + c4;
        row[0] = v.x; row[1] = v.y; row[2] = v.z; row[3] = v.w;
    }
    __syncthreads();
    #pragma unroll
    for (int s = 0; s < 4; s++) {
        int idx = tid + s * 256;
        int nn = idx >> 4, kc = (idx & 15) * 4;
        ushort4 o = make_ushort4(f2b(sm[(kc + 0) * 65 + nn]), f2b(sm[(kc + 1) * 65 + nn]),
                                 f2b(sm[(kc + 2) * 65 + nn]), f2b(sm[(kc + 3) * 65 + nn]));
        *(ushort4*)&Wdst[(size_t)(n0 + nn) * K + k0 + kc] = o;
    }
}

// ---------------------------------------------------------------------------
// prep1: only L1's dependencies.  0: route; 1..256: Xb; 257..2304: W1t.
// ---------------------------------------------------------------------------
#define P1_TOT (1 + 256 + 2048)

__global__ __launch_bounds__(256) void prep1_kernel(
    const float* __restrict__ xs, const float* __restrict__ xp,
    const float* __restrict__ W1, const int* __restrict__ label,
    int* __restrict__ meta, int* __restrict__ perm,
    u16* __restrict__ Xb, u16* __restrict__ W1t)
{
    __shared__ __align__(16) float sm[64 * 65];
    const int bid = blockIdx.x;
    const int tid = threadIdx.x;

    if (bid == 0) {
        int* cnt = (int*)sm;
        int* off = cnt + En;
        if (tid < En) cnt[tid] = 0;
        __syncthreads();
        for (int b = tid; b < Bn; b += 256) atomicAdd(&cnt[label[b]], 1);
        __syncthreads();
        if (tid == 0) {
            int run = 0;
            for (int e = 0; e < En; e++) { off[e] = run; run += cnt[e]; }
            off[En] = run;
        }
        __syncthreads();
        if (tid < En) cnt[tid] = off[tid];
        __syncthreads();
        for (int b = tid; b < Bn; b += 256) {
            int e = label[b];
            perm[atomicAdd(&cnt[e], 1)] = b;
        }
        if (tid <= En) meta[tid] = off[tid];
    } else if (bid < 257) {
        int r0 = (bid - 1) * 16;
        #pragma unroll 4
        for (int s = 0; s < 16; s++) {
            int r = r0 + s;
            int k = tid * 4;
            const float* src = (k < Ln) ? (xp + (size_t)r * Ln + k)
                                        : (xs + (size_t)r * Ln + (k - Ln));
            float4 v = *(const float4*)src;
            *(ushort4*)&Xb[(size_t)r * K1n + k] =
                make_ushort4(f2b(v.x), f2b(v.y), f2b(v.z), f2b(v.w));
        }
    } else {
        int b = bid - 257;
        int e = b >> 8, rem = b & 255;
        int k0 = (rem >> 4) * 64, n0 = (rem & 15) * 64;
        wtrans64(W1 + (size_t)e * K1n * H1n, W1t + (size_t)e * H1n * K1n,
                 K1n, H1n, k0, n0, tid, sm);
    }
}

// ---------------------------------------------------------------------------
// Grouped bf16 MFMA GEMM, 64x64 tile, BK=64, double-buffered async K-loop.
// 4 waves/block, each a 32x32 quadrant (2x2 MFMA x 2 k-halves per iter).
// PREP2 (L1 instance): blocks >= NTR*NTC run W2t/W3t/out-init jobs instead
// (they dispatch after the GEMM blocks and fill CU-retirement gaps).
// FUSE3 (L2 instance): layer-3 k-split epilogue, atomicAdd into outf
// (pre-initialized with b3 by the PREP2 out-init job of the L1 launch).
// ---------------------------------------------------------------------------
template <int K, int N, bool GATHER, bool FUSE3, bool PREP2>
__global__ __launch_bounds__(256) void mfma_gemm(
    const u16* __restrict__ A, const u16* __restrict__ Wt,
    const float* __restrict__ bias, const int* __restrict__ meta,
    const int* __restrict__ perm, u16* __restrict__ outb,
    const u16* __restrict__ Wt3, float* __restrict__ outf,
    const float* __restrict__ W2f, const float* __restrict__ W3f,
    const float* __restrict__ b3v, const int* __restrict__ labelv,
    u16* __restrict__ W2t_o, u16* __restrict__ W3t_o)
{
    constexpr int TM = 64, BK = 64;
    constexpr int T = K / BK;
    constexpr int NTC = N / 64;
    __shared__ __align__(16) u16 SM[16384];   // 2 stages x (A 8KB + B 8KB) = 32 KB

    const int tid = threadIdx.x;
    const int bx = blockIdx.x;

    if (PREP2 && bx >= NTR * NTC) {
        int jb = bx - NTR * NTC;
        if (jb < 1024) {               // W2 transpose
            int e = jb >> 7, rem = jb & 127;
            int k0 = (rem >> 3) * 64, n0 = (rem & 7) * 64;
            wtrans64(W2f + (size_t)e * H1n * H2n, W2t_o + (size_t)e * H2n * H1n,
                     H1n, H2n, k0, n0, tid, (float*)SM);
        } else if (jb < 1024 + 128) {  // W3 transpose+pad
            int b = jb - 1024;
            int e = b >> 4, k0 = (b & 15) * 32;
            const float* src = W3f + (size_t)e * H2n * Cn;
            u16* dst = W3t_o + (size_t)e * NP3 * H2n;
            float* t = (float*)SM;     // [32][41]
            #pragma unroll
            for (int s = 0; s < 5; s++) {
                int idx = tid + s * 256;
                int kk = idx / Cn, nn = idx - kk * Cn;
                if (kk < 32) t[kk * 41 + nn] = src[(size_t)(k0 + kk) * Cn + nn];
            }
            __syncthreads();
            #pragma unroll
            for (int s = 0; s < 6; s++) {
                int idx = tid + s * 256;
                int nn = idx >> 5, kk = idx & 31;
                float v = (nn < Cn) ? t[kk * 41 + nn] : 0.f;
                dst[(size_t)nn * H2n + k0 + kk] = f2b(v);
            }
        } else {                       // out bias pre-init
            int b = jb - (1024 + 128);
            int r0 = b * 64;
            #pragma unroll
            for (int s = 0; s < 10; s++) {
                int idx = tid + s * 256;
                int r = r0 + idx / Cn;
                int c = idx - (idx / Cn) * Cn;
                outf[(size_t)r * Cn + c] = b3v[labelv[r] * Cn + c];
            }
        }
        return;
    }

    const int rt = bx % NTR;
    const int col0 = (bx / NTR) * 64;

    int expert = -1, row0 = 0, rowmax = 0, acc_t = 0;
    int prev = meta[0];
    #pragma unroll
    for (int e = 0; e < En; e++) {
        int nxt = meta[e + 1];
        int c = nxt - prev;
        int t = (c + TM - 1) / TM;
        if (expert < 0 && rt < acc_t + t) {
            expert = e; row0 = prev + (rt - acc_t) * TM; rowmax = nxt - 1;
        }
        acc_t += t; prev = nxt;
    }
    if (expert < 0) return;

    const u16* Wexp = Wt + (size_t)expert * N * K;

    const int lane = tid & 63;
    const int wid = tid >> 6;
    const int wm = (wid & 1) * 32;
    const int wn = (wid >> 1) * 32;
    const int l15 = lane & 15;
    const int lq = lane >> 4;

    // staging: 512 slots/matrix (idx = tid + s*256): row rl = idx>>3,
    // chunk pos c = idx&7 holds global k-chunk c^(rl&7); LDS off = idx*16B.
    const u16* aptr[2]; const u16* bptr[2];
    int aoff[2], boff[2];
    #pragma unroll
    for (int s = 0; s < 2; s++) {
        int idx = tid + s * 256;
        int rl = idx >> 3, c = idx & 7;
        int kq = c ^ (rl & 7);
        int rg = row0 + rl; if (rg > rowmax) rg = rowmax;
        if (GATHER) rg = perm[rg];
        aptr[s] = A + (size_t)rg * K + kq * 8;
        bptr[s] = Wexp + (size_t)(col0 + rl) * K + kq * 8;
        aoff[s] = idx * 8;
        boff[s] = 4096 + idx * 8;
    }
    const int csw = l15 & 7;

    f32x4 acc[2][2];
    #pragma unroll
    for (int i = 0; i < 2; i++)
        #pragma unroll
        for (int j = 0; j < 2; j++) acc[i][j] = (f32x4){0.f, 0.f, 0.f, 0.f};

    // prologue: tile 0 -> stage 0
    #pragma unroll
    for (int s = 0; s < 2; s++) {
        g2l16(aptr[s], &SM[aoff[s]]);
        g2l16(bptr[s], &SM[boff[s]]);
    }

    for (int t = 0; t < T; t++) {
        __syncthreads();
        const u16* As = &SM[(t & 1) * 8192];
        const u16* Bs = As + 4096;
        if (t + 1 < T) {
            int base = ((t + 1) & 1) * 8192;
            int ko = (t + 1) * BK;
            #pragma unroll
            for (int s = 0; s < 2; s++) {
                g2l16(aptr[s] + ko, &SM[base + aoff[s]]);
                g2l16(bptr[s] + ko, &SM[base + boff[s]]);
            }
        }
        #pragma unroll
        for (int h = 0; h < 2; h++) {
            const int ksw = ((h * 4 + lq) ^ csw) << 3;
            bf16x8 af[2], bf[2];
            #pragma unroll
            for (int i = 0; i < 2; i++)
                af[i] = *(const bf16x8*)&As[(wm + i * 16 + l15) * BK + ksw];
            #pragma unroll
            for (int j = 0; j < 2; j++)
                bf[j] = *(const bf16x8*)&Bs[(wn + j * 16 + l15) * BK + ksw];
            #pragma unroll
            for (int i = 0; i < 2; i++)
                #pragma unroll
                for (int j = 0; j < 2; j++)
                    acc[i][j] = __builtin_amdgcn_mfma_f32_16x16x32_bf16(
                        af[i], bf[j], acc[i][j], 0, 0, 0);
        }
    }

    if (!FUSE3) {
        // bias + ELU -> global bf16.  C/D: col=l15, row=lq*4+reg
        #pragma unroll
        for (int i = 0; i < 2; i++) {
            #pragma unroll
            for (int j = 0; j < 2; j++) {
                int col = col0 + wn + j * 16 + l15;
                float bv = bias[expert * N + col];
                #pragma unroll
                for (int r = 0; r < 4; r++) {
                    int grow = row0 + wm + i * 16 + lq * 4 + r;
                    if (grow <= rowmax) {
                        float v = acc[i][j][r] + bv;
                        v = (v > 0.f) ? v : (expf(v) - 1.f);
                        outb[(size_t)grow * N + col] = f2b(v);
                    }
                }
            }
        }
    } else {
        // fused layer 3: k-split over this block's 64 h-cols
        __syncthreads();
        u16* H = &SM[0];   // [64][72] bf16
        #pragma unroll
        for (int i = 0; i < 2; i++) {
            #pragma unroll
            for (int j = 0; j < 2; j++) {
                int col = wn + j * 16 + l15;
                float bv = bias[expert * N + col0 + col];
                #pragma unroll
                for (int r = 0; r < 4; r++) {
                    float v = acc[i][j][r] + bv;
                    v = (v > 0.f) ? v : (expf(v) - 1.f);
                    H[(wm + i * 16 + lq * 4 + r) * 72 + col] = f2b(v);
                }
            }
        }
        __syncthreads();
        const int rh = wid * 16;
        f32x4 a3[3];
        #pragma unroll
        for (int j = 0; j < 3; j++) a3[j] = (f32x4){0.f, 0.f, 0.f, 0.f};
        #pragma unroll
        for (int ki = 0; ki < 2; ki++) {
            bf16x8 ha = *(const bf16x8*)&H[(rh + l15) * 72 + ki * 32 + lq * 8];
            #pragma unroll
            for (int j = 0; j < 3; j++) {
                bf16x8 wb = *(const bf16x8*)
                    &Wt3[((size_t)expert * NP3 + j * 16 + l15) * H2n + col0 + ki * 32 + lq * 8];
                a3[j] = __builtin_amdgcn_mfma_f32_16x16x32_bf16(ha, wb, a3[j], 0, 0, 0);
            }
        }
        #pragma unroll
        for (int j = 0; j < 3; j++) {
            int col = j * 16 + l15;
            if (col < Cn) {
                #pragma unroll
                for (int r = 0; r < 4; r++) {
                    int grow = row0 + rh + lq * 4 + r;
                    if (grow <= rowmax)
                        atomicAdd(&outf[(size_t)perm[grow] * Cn + col], a3[j][r]);
                }
            }
        }
    }
}

// ---------------------------------------------------------------------------
extern "C" void kernel_launch(void* const* d_in, const int* in_sizes, int n_in,
                              void* d_out, int out_size, void* d_ws, size_t ws_size,
                              hipStream_t stream)
{
    const float* xs = (const float*)d_in[0];
    const float* xp = (const float*)d_in[1];
    const float* W1 = (const float*)d_in[2];
    const float* b1 = (const float*)d_in[3];
    const float* W2 = (const float*)d_in[4];
    const float* b2 = (const float*)d_in[5];
    const float* W3 = (const float*)d_in[6];
    const float* b3 = (const float*)d_in[7];
    const int* label = (const int*)d_in[8];
    float* out = (float*)d_out;

    char* ws = (char*)d_ws;
    int* meta = (int*)ws;                                    // 64 B
    int* perm = (int*)(ws + 64);                             // 16 KB
    u16* Xb  = (u16*)(ws + (64 << 10));                      // 8 MB [4096][1024] (orig)
    u16* W1t = (u16*)(ws + (64 << 10) + (8  << 20));         // 16 MB [8][1024][1024]
    u16* W2t = (u16*)(ws + (64 << 10) + (24 << 20));         // 8 MB  [8][512][1024]
    u16* h1b = (u16*)(ws + (64 << 10) + (32 << 20));         // 8 MB  [4096][1024] (sorted)
    u16* W3t = (u16*)(ws + (64 << 10) + (40 << 20));         // 393 KB [8][48][512]

    prep1_kernel<<<P1_TOT, 256, 0, stream>>>(
        xs, xp, W1, label, meta, perm, Xb, W1t);

    // L1 GEMM (1152 blocks) + prep2 jobs (1216 blocks, tail-filling)
    mfma_gemm<K1n, H1n, true, false, true><<<72 * 16 + 1216, 256, 0, stream>>>(
        Xb, W1t, b1, meta, perm, h1b, nullptr, out,
        W2, W3, b3, label, W2t, W3t);

    // L2 + fused L3 (576 blocks)
    mfma_gemm<H1n, H2n, false, true, false><<<72 * 8, 256, 0, stream>>>(
        h1b, W2t, b2, meta, perm, nullptr, W3t, out,
        nullptr, nullptr, nullptr, nullptr, nullptr, nullptr);
}